// Round 1
// baseline (1126.608 us; speedup 1.0000x reference)
//
#include <hip/hip_runtime.h>
#include <math.h>

#define P 65536   // H*W
#define HH 256
#define WW 256

__device__ __forceinline__ float act_f(float v, int act) {
    switch (act) {
        case 1: return v > 0.f ? v : 0.f;                    // relu
        case 2: return 1.f / (1.f + expf(-v));               // sigmoid
        case 3: return v > 0.f ? v : 0.2f * v;               // lrelu
        default: return v;
    }
}

// Generic 3x3 conv, pad=1, NCHW, B=1. One thread per (co, pixel).
// flip: input value v -> 1-v (padding remains 0, matching flip-before-pad).
__global__ void conv3x3_k(const float* __restrict__ in, const float* __restrict__ w,
                          const float* __restrict__ bias, float* __restrict__ out,
                          int Cin, int act, int flip) {
    int p  = blockIdx.x * blockDim.x + threadIdx.x;
    int co = blockIdx.y;
    if (p >= P) return;
    int h = p >> 8, x0 = p & 255;
    float acc = bias[co];
    const float* wc = w + co * Cin * 9;
    for (int c = 0; c < Cin; ++c) {
        const float* ic = in + c * P;
        const float* wcc = wc + c * 9;
        #pragma unroll
        for (int kh = 0; kh < 3; ++kh) {
            int hh = h + kh - 1;
            if ((unsigned)hh >= (unsigned)HH) continue;
            #pragma unroll
            for (int kw = 0; kw < 3; ++kw) {
                int wx = x0 + kw - 1;
                if ((unsigned)wx >= (unsigned)WW) continue;
                float v = ic[hh * WW + wx];
                if (flip) v = 1.0f - v;
                acc = fmaf(v, wcc[kh * 3 + kw], acc);
            }
        }
    }
    out[co * P + p] = act_f(acc, act);
}

// Generic 1x1 conv. One thread per (co, pixel).
__global__ void conv1x1_k(const float* __restrict__ in, const float* __restrict__ w,
                          const float* __restrict__ bias, float* __restrict__ out,
                          int Cin, int act, int flip) {
    int p  = blockIdx.x * blockDim.x + threadIdx.x;
    int co = blockIdx.y;
    if (p >= P) return;
    float acc = bias[co];
    const float* wc = w + co * Cin;
    for (int c = 0; c < Cin; ++c) {
        float v = in[c * P + p];
        if (flip) v = 1.0f - v;
        acc = fmaf(v, wc[c], acc);
    }
    out[co * P + p] = act_f(acc, act);
}

// EU/mean head: xs[t,o,p] = tanh(sum_c mask[t,c]*w4[o,c]*x[c,p] + b[o]) + ms[o,p]
// EU = var over t (ddof=1), MEAN = mean over t.
__global__ void xsstats_k(const float* __restrict__ x, const float* __restrict__ masks_u,
                          const float* __restrict__ w4, const float* __restrict__ b4,
                          const float* __restrict__ msin,
                          float* __restrict__ EU, float* __restrict__ MEAN) {
    __shared__ float mw[10 * 4 * 64];   // [t][o][c]
    for (int i = threadIdx.x; i < 2560; i += blockDim.x) {
        int t = i >> 8;
        int o = (i >> 6) & 3;
        int c = i & 63;
        float m = (masks_u[t * 64 + c] < 0.8f) ? 1.0f : 0.0f;
        mw[i] = m * w4[o * 64 + c];
    }
    __syncthreads();
    int p = blockIdx.x * blockDim.x + threadIdx.x;
    if (p >= P) return;
    float xv[64];
    #pragma unroll
    for (int c = 0; c < 64; ++c) xv[c] = x[c * P + p];
    #pragma unroll
    for (int o = 0; o < 4; ++o) {
        float msv = msin[o * P + p];
        float bo  = b4[o];
        float vals[10];
        float s = 0.f;
        #pragma unroll
        for (int t = 0; t < 10; ++t) {
            float a = bo;
            const float* mwp = &mw[t * 256 + o * 64];
            #pragma unroll
            for (int c = 0; c < 64; ++c) a = fmaf(mwp[c], xv[c], a);
            float v = tanhf(a) + msv;
            vals[t] = v;
            s += v;
        }
        float m = s * 0.1f;
        MEAN[o * P + p] = m;
        float var = 0.f;
        #pragma unroll
        for (int t = 0; t < 10; ++t) { float d = vals[t] - m; var = fmaf(d, d, var); }
        EU[o * P + p] = var * (1.0f / 9.0f);
    }
}

// uaconv patch-einsum: y[m,p] = sum_{n,k} x[n, p+off(k)] * spec[n,p] * spat[k,p] * Wk[m,n,k]
// x channels 0..31 from xa, 32..63 from xb (concat never materialized).
// Each block: 16 of 32 output channels (blockIdx.y), weights staged in LDS (36 KB).
__global__ void uaconv_k(const float* __restrict__ xa, const float* __restrict__ xb,
                         const float* __restrict__ spec, const float* __restrict__ spat,
                         const float* __restrict__ Wk, float* __restrict__ y) {
    __shared__ float w[16 * 64 * 9];
    int mbase = blockIdx.y * 16;
    for (int i = threadIdx.x; i < 16 * 64 * 9; i += blockDim.x)
        w[i] = Wk[mbase * 576 + i];
    __syncthreads();
    int p = blockIdx.x * blockDim.x + threadIdx.x;
    if (p >= P) return;
    int h = p >> 8, x0 = p & 255;
    float spatv[9];
    #pragma unroll
    for (int k = 0; k < 9; ++k) spatv[k] = spat[k * P + p];
    float acc[16];
    #pragma unroll
    for (int m = 0; m < 16; ++m) acc[m] = 0.f;
    for (int n = 0; n < 64; ++n) {
        const float* xc = (n < 32) ? (xa + n * P) : (xb + (n - 32) * P);
        float sp = spec[n * P + p];
        float q[9];
        #pragma unroll
        for (int kh = 0; kh < 3; ++kh) {
            int hh = h + kh - 1;
            #pragma unroll
            for (int kw = 0; kw < 3; ++kw) {
                int wx = x0 + kw - 1;
                float v = ((unsigned)hh < 256u && (unsigned)wx < 256u) ? xc[hh * WW + wx] : 0.f;
                q[kh * 3 + kw] = v * sp * spatv[kh * 3 + kw];
            }
        }
        const float* wn = &w[n * 9];
        #pragma unroll
        for (int m = 0; m < 16; ++m) {
            #pragma unroll
            for (int k = 0; k < 9; ++k)
                acc[m] = fmaf(wn[m * 576 + k], q[k], acc[m]);
        }
    }
    #pragma unroll
    for (int m = 0; m < 16; ++m)
        y[(mbase + m) * P + p] = acc[m];
}

extern "C" void kernel_launch(void* const* d_in, const int* in_sizes, int n_in,
                              void* d_out, int out_size, void* d_ws, size_t ws_size,
                              hipStream_t stream) {
    const float* F1       = (const float*)d_in[0];
    const float* ms       = (const float*)d_in[1];
    const float* pan      = (const float*)d_in[2];
    const float* masks_u  = (const float*)d_in[3];
    const float* ue_conv_w = (const float*)d_in[4];
    const float* ue_conv_b = (const float*)d_in[5];
    const float* ue_out_w  = (const float*)d_in[6];
    const float* ue_out_b  = (const float*)d_in[7];
    const float* ue_aue_w  = (const float*)d_in[8];
    const float* ue_aue_b  = (const float*)d_in[9];
    const float* conv1_w   = (const float*)d_in[10];
    const float* conv1_b   = (const float*)d_in[11];
    const float* conv2_w   = (const float*)d_in[12];
    const float* conv2_b   = (const float*)d_in[13];
    // block 1: indices 14..26, block 2: 27..39
    const float* spa1_w0 = (const float*)d_in[14];
    const float* spa1_b0 = (const float*)d_in[15];
    const float* spa1_w1 = (const float*)d_in[16];
    const float* spa1_b1 = (const float*)d_in[17];
    const float* spa1_w2 = (const float*)d_in[18];
    const float* spa1_b2 = (const float*)d_in[19];
    const float* spe1_w0 = (const float*)d_in[20];
    const float* spe1_b0 = (const float*)d_in[21];
    const float* spe1_w1 = (const float*)d_in[22];
    const float* spe1_b1 = (const float*)d_in[23];
    const float* spe1_w2 = (const float*)d_in[24];
    const float* spe1_b2 = (const float*)d_in[25];
    const float* ua1_w   = (const float*)d_in[26];
    const float* spa2_w0 = (const float*)d_in[27];
    const float* spa2_b0 = (const float*)d_in[28];
    const float* spa2_w1 = (const float*)d_in[29];
    const float* spa2_b1 = (const float*)d_in[30];
    const float* spa2_w2 = (const float*)d_in[31];
    const float* spa2_b2 = (const float*)d_in[32];
    const float* spe2_w0 = (const float*)d_in[33];
    const float* spe2_b0 = (const float*)d_in[34];
    const float* spe2_w1 = (const float*)d_in[35];
    const float* spe2_b1 = (const float*)d_in[36];
    const float* spe2_w2 = (const float*)d_in[37];
    const float* spe2_b2 = (const float*)d_in[38];
    const float* ua2_w   = (const float*)d_in[39];

    float* out  = (float*)d_out;
    float* AU   = out;             // 4*P
    float* EU   = out + 4 * P;     // 4*P
    float* MEAN = out + 8 * P;     // 4*P
    float* FOUT = out + 12 * P;    // 32*P

    float* ws   = (float*)d_ws;
    float* x    = ws;                 // 64P (dead after AU; region reused as bufA)
    float* bufA = ws;                 // 64P (spec chain ping)
    float* bufB = ws + 64 * P;        // 64P (spec chain pong)
    float* spa0 = ws + 128 * P;       // 9P
    float* spa1b = ws + 137 * P;      // 9P
    float* ybuf = ws + 146 * P;       // 32P
    float* f2   = ws + 178 * P;       // 32P

    dim3 blk(256);
    dim3 gP(P / 256);

    // 1. x = conv3x3(F_1; 32->64)
    conv3x3_k<<<dim3(P / 256, 64), blk, 0, stream>>>(F1, ue_conv_w, ue_conv_b, x, 32, 0, 0);
    // 2. EU / mean
    xsstats_k<<<gP, blk, 0, stream>>>(x, masks_u, ue_out_w, ue_out_b, ms, EU, MEAN);
    // 3. AU = sigmoid(conv3x3(x; 64->4))
    conv3x3_k<<<dim3(P / 256, 4), blk, 0, stream>>>(x, ue_aue_w, ue_aue_b, AU, 64, 2, 0);

    // ---- uaconv 1 (U = EU, inputs F1 || pan) ----
    conv3x3_k<<<dim3(P / 256, 9), blk, 0, stream>>>(EU, spa1_w0, spa1_b0, spa0, 4, 1, 0);
    conv1x1_k<<<dim3(P / 256, 9), blk, 0, stream>>>(spa0, spa1_w1, spa1_b1, spa1b, 9, 1, 0);
    conv1x1_k<<<dim3(P / 256, 9), blk, 0, stream>>>(spa1b, spa1_w2, spa1_b2, spa0, 9, 2, 0); // spat1 -> spa0
    conv1x1_k<<<dim3(P / 256, 64), blk, 0, stream>>>(EU, spe1_w0, spe1_b0, bufA, 4, 1, 0);   // overwrites x (dead)
    conv1x1_k<<<dim3(P / 256, 64), blk, 0, stream>>>(bufA, spe1_w1, spe1_b1, bufB, 64, 1, 0);
    conv1x1_k<<<dim3(P / 256, 64), blk, 0, stream>>>(bufB, spe1_w2, spe1_b2, bufA, 64, 2, 0); // spec1 -> bufA
    uaconv_k<<<dim3(P / 256, 2), blk, 0, stream>>>(F1, pan, bufA, spa0, ua1_w, ybuf);
    // F_2 = lrelu(conv1x1(y1; 32->32))
    conv1x1_k<<<dim3(P / 256, 32), blk, 0, stream>>>(ybuf, conv1_w, conv1_b, f2, 32, 3, 0);

    // ---- uaconv 2 (U = 1-EU, inputs F1 || F_2) ----
    conv3x3_k<<<dim3(P / 256, 9), blk, 0, stream>>>(EU, spa2_w0, spa2_b0, spa0, 4, 1, 1);
    conv1x1_k<<<dim3(P / 256, 9), blk, 0, stream>>>(spa0, spa2_w1, spa2_b1, spa1b, 9, 1, 0);
    conv1x1_k<<<dim3(P / 256, 9), blk, 0, stream>>>(spa1b, spa2_w2, spa2_b2, spa0, 9, 2, 0); // spat2 -> spa0
    conv1x1_k<<<dim3(P / 256, 64), blk, 0, stream>>>(EU, spe2_w0, spe2_b0, bufA, 4, 1, 1);
    conv1x1_k<<<dim3(P / 256, 64), blk, 0, stream>>>(bufA, spe2_w1, spe2_b1, bufB, 64, 1, 0);
    conv1x1_k<<<dim3(P / 256, 64), blk, 0, stream>>>(bufB, spe2_w2, spe2_b2, bufA, 64, 2, 0); // spec2 -> bufA
    uaconv_k<<<dim3(P / 256, 2), blk, 0, stream>>>(F1, f2, bufA, spa0, ua2_w, ybuf);
    // F_out = lrelu(conv1x1(y2; 32->32))
    conv1x1_k<<<dim3(P / 256, 32), blk, 0, stream>>>(ybuf, conv2_w, conv2_b, FOUT, 32, 3, 0);
}

// Round 2
// 414.045 us; speedup vs baseline: 2.7210x; 2.7210x over previous
//
#include <hip/hip_runtime.h>
#include <math.h>

#define P 65536   // H*W
#define HH 256
#define WW 256

// ---------------------------------------------------------------------------
// Register-blocked 3x3 conv, pad=1, NCHW, B=1.
// Thread: PIX consecutive pixels (same row) x NCO output channels.
// Block: 256 threads -> 256*PIX pixels; blockIdx.y -> co group.
// Weights staged in LDS as [ci][k][co] for broadcast float4 reads.
// ACT: 0 = none, 2 = sigmoid.
template<int CIN, int NCO, int PIX, int ACT>
__global__ void conv3x3_rb(const float* __restrict__ in, const float* __restrict__ wsrc,
                           const float* __restrict__ bias, float* __restrict__ out) {
    __shared__ float wl[CIN * 9 * NCO];
    const int cob = blockIdx.y * NCO;
    for (int i = threadIdx.x; i < CIN * 9 * NCO; i += 256) {
        int co = i % NCO;
        int rest = i / NCO;              // ci*9 + k
        int ci = rest / 9, k = rest % 9;
        wl[i] = wsrc[(cob + co) * CIN * 9 + ci * 9 + k];
    }
    __syncthreads();
    const int pixb = (blockIdx.x * 256 + threadIdx.x) * PIX;
    const int h = pixb >> 8, x0 = pixb & 255;
    float acc[NCO][PIX];
    #pragma unroll
    for (int co = 0; co < NCO; ++co) {
        float b = bias[cob + co];
        #pragma unroll
        for (int j = 0; j < PIX; ++j) acc[co][j] = b;
    }
    for (int ci = 0; ci < CIN; ++ci) {
        const float* icp = in + ci * P;
        #pragma unroll
        for (int kh = 0; kh < 3; ++kh) {
            int hh = h + kh - 1;
            if ((unsigned)hh >= 256u) continue;   // wave-uniform (whole wave same row)
            const float* rp = icp + hh * WW;
            float v[PIX + 2];
            v[0] = (x0 > 0) ? rp[x0 - 1] : 0.f;
            if constexpr (PIX == 4) {
                float4 m = *(const float4*)(rp + x0);
                v[1] = m.x; v[2] = m.y; v[3] = m.z; v[4] = m.w;
            } else {
                float2 m = *(const float2*)(rp + x0);
                v[1] = m.x; v[2] = m.y;
            }
            v[PIX + 1] = (x0 + PIX < 256) ? rp[x0 + PIX] : 0.f;
            #pragma unroll
            for (int kw = 0; kw < 3; ++kw) {
                const float* wp = &wl[(ci * 9 + kh * 3 + kw) * NCO];
                #pragma unroll
                for (int co = 0; co < NCO; ++co) {
                    float wv = wp[co];
                    #pragma unroll
                    for (int j = 0; j < PIX; ++j)
                        acc[co][j] = fmaf(v[kw + j], wv, acc[co][j]);
                }
            }
        }
    }
    #pragma unroll
    for (int co = 0; co < NCO; ++co) {
        float* op = out + (cob + co) * P + pixb;
        #pragma unroll
        for (int j = 0; j < PIX; ++j) {
            float r = acc[co][j];
            if constexpr (ACT == 2) r = 1.f / (1.f + expf(-r));
            op[j] = r;
        }
    }
}

// ---------------------------------------------------------------------------
// EU/mean head: xs[t,o,p] = tanh(sum_c mask[t,c]*w4[o,c]*x[c,p] + b[o]) + ms[o,p]
__global__ void xsstats_k(const float* __restrict__ x, const float* __restrict__ masks_u,
                          const float* __restrict__ w4, const float* __restrict__ b4,
                          const float* __restrict__ msin,
                          float* __restrict__ EU, float* __restrict__ MEAN) {
    __shared__ float mw[10 * 4 * 64];   // [t][o][c]
    for (int i = threadIdx.x; i < 2560; i += blockDim.x) {
        int t = i >> 8;
        int o = (i >> 6) & 3;
        int c = i & 63;
        float m = (masks_u[t * 64 + c] < 0.8f) ? 1.0f : 0.0f;
        mw[i] = m * w4[o * 64 + c];
    }
    __syncthreads();
    int p = blockIdx.x * blockDim.x + threadIdx.x;
    float xv[64];
    #pragma unroll
    for (int c = 0; c < 64; ++c) xv[c] = x[c * P + p];
    #pragma unroll
    for (int o = 0; o < 4; ++o) {
        float msv = msin[o * P + p];
        float bo  = b4[o];
        float vals[10];
        float s = 0.f;
        #pragma unroll
        for (int t = 0; t < 10; ++t) {
            float a = bo;
            const float* mwp = &mw[t * 256 + o * 64];
            #pragma unroll
            for (int c = 0; c < 64; ++c) a = fmaf(mwp[c], xv[c], a);
            float v = tanhf(a) + msv;
            vals[t] = v;
            s += v;
        }
        float m = s * 0.1f;
        MEAN[o * P + p] = m;
        float var = 0.f;
        #pragma unroll
        for (int t = 0; t < 10; ++t) { float d = vals[t] - m; var = fmaf(d, d, var); }
        EU[o * P + p] = var * (1.0f / 9.0f);
    }
}

// ---------------------------------------------------------------------------
// Fused spatial-gate chain: spat = sigmoid(1x1(relu(1x1(relu(conv3x3(U,4->9))))))
// flip: U -> 1-U on valid (non-pad) samples only.
__global__ void spa_fused_k(const float* __restrict__ U,
                            const float* __restrict__ w0, const float* __restrict__ b0,
                            const float* __restrict__ w1, const float* __restrict__ b1,
                            const float* __restrict__ w2, const float* __restrict__ b2,
                            float* __restrict__ spat, int flip) {
    __shared__ float l0[324];   // (9,4,3,3) flat
    __shared__ float l1[81];    // (9,9)
    __shared__ float l2[81];
    for (int i = threadIdx.x; i < 324; i += 256) l0[i] = w0[i];
    if (threadIdx.x < 81) { l1[threadIdx.x] = w1[threadIdx.x]; l2[threadIdx.x] = w2[threadIdx.x]; }
    __syncthreads();
    int p = blockIdx.x * 256 + threadIdx.x;
    int h = p >> 8, x0 = p & 255;
    float u[4][9];
    #pragma unroll
    for (int ci = 0; ci < 4; ++ci) {
        const float* up = U + ci * P;
        #pragma unroll
        for (int kh = 0; kh < 3; ++kh) {
            int hh = h + kh - 1;
            bool hok = (unsigned)hh < 256u;
            #pragma unroll
            for (int kw = 0; kw < 3; ++kw) {
                int wx = x0 + kw - 1;
                bool ok = hok && (unsigned)wx < 256u;
                float v = ok ? up[hh * WW + wx] : 0.f;
                if (flip && ok) v = 1.f - v;
                u[ci][kh * 3 + kw] = v;
            }
        }
    }
    float a1[9];
    #pragma unroll
    for (int co = 0; co < 9; ++co) {
        float s = b0[co];
        #pragma unroll
        for (int ci = 0; ci < 4; ++ci)
            #pragma unroll
            for (int k = 0; k < 9; ++k)
                s = fmaf(u[ci][k], l0[co * 36 + ci * 9 + k], s);
        a1[co] = fmaxf(s, 0.f);
    }
    float a2[9];
    #pragma unroll
    for (int co = 0; co < 9; ++co) {
        float s = b1[co];
        #pragma unroll
        for (int ci = 0; ci < 9; ++ci) s = fmaf(a1[ci], l1[co * 9 + ci], s);
        a2[co] = fmaxf(s, 0.f);
    }
    #pragma unroll
    for (int co = 0; co < 9; ++co) {
        float s = b2[co];
        #pragma unroll
        for (int ci = 0; ci < 9; ++ci) s = fmaf(a2[ci], l2[co * 9 + ci], s);
        spat[co * P + p] = 1.f / (1.f + expf(-s));
    }
}

// ---------------------------------------------------------------------------
// Fused spectral-gate MLP: spec = sigmoid(W2 relu(W1 relu(W0 U + b0) + b1) + b2)
__global__ __launch_bounds__(256, 1) void spe_fused_k(
        const float* __restrict__ U, int flip,
        const float* __restrict__ w0, const float* __restrict__ b0,
        const float* __restrict__ w1, const float* __restrict__ b1,
        const float* __restrict__ w2, const float* __restrict__ b2,
        float* __restrict__ spec) {
    __shared__ float w0l[256];    // (64,4) flat
    __shared__ float w1t[4096];   // [ci][co] transposed
    __shared__ float w2t[4096];
    for (int i = threadIdx.x; i < 256; i += 256) w0l[i] = w0[i];
    for (int i = threadIdx.x; i < 4096; i += 256) {
        int co = i & 63, ci = i >> 6;
        w1t[ci * 64 + co] = w1[co * 64 + ci];
        w2t[ci * 64 + co] = w2[co * 64 + ci];
    }
    __syncthreads();
    int p = blockIdx.x * 256 + threadIdx.x;
    float u[4];
    #pragma unroll
    for (int ci = 0; ci < 4; ++ci) {
        float v = U[ci * P + p];
        u[ci] = flip ? 1.f - v : v;
    }
    float h1[64];
    #pragma unroll
    for (int co = 0; co < 64; ++co) {
        float s = b0[co];
        #pragma unroll
        for (int ci = 0; ci < 4; ++ci) s = fmaf(u[ci], w0l[co * 4 + ci], s);
        h1[co] = fmaxf(s, 0.f);
    }
    float h2[64];
    #pragma unroll
    for (int co = 0; co < 64; ++co) h2[co] = b1[co];
    #pragma unroll
    for (int ci = 0; ci < 64; ++ci) {
        float hv = h1[ci];
        const float4* wp = (const float4*)&w1t[ci * 64];
        #pragma unroll
        for (int cq = 0; cq < 16; ++cq) {
            float4 wv = wp[cq];
            h2[cq * 4 + 0] = fmaf(hv, wv.x, h2[cq * 4 + 0]);
            h2[cq * 4 + 1] = fmaf(hv, wv.y, h2[cq * 4 + 1]);
            h2[cq * 4 + 2] = fmaf(hv, wv.z, h2[cq * 4 + 2]);
            h2[cq * 4 + 3] = fmaf(hv, wv.w, h2[cq * 4 + 3]);
        }
    }
    #pragma unroll
    for (int co = 0; co < 64; ++co) h2[co] = fmaxf(h2[co], 0.f);
    float h3[64];
    #pragma unroll
    for (int co = 0; co < 64; ++co) h3[co] = b2[co];
    #pragma unroll
    for (int ci = 0; ci < 64; ++ci) {
        float hv = h2[ci];
        const float4* wp = (const float4*)&w2t[ci * 64];
        #pragma unroll
        for (int cq = 0; cq < 16; ++cq) {
            float4 wv = wp[cq];
            h3[cq * 4 + 0] = fmaf(hv, wv.x, h3[cq * 4 + 0]);
            h3[cq * 4 + 1] = fmaf(hv, wv.y, h3[cq * 4 + 1]);
            h3[cq * 4 + 2] = fmaf(hv, wv.z, h3[cq * 4 + 2]);
            h3[cq * 4 + 3] = fmaf(hv, wv.w, h3[cq * 4 + 3]);
        }
    }
    #pragma unroll
    for (int co = 0; co < 64; ++co)
        spec[co * P + p] = 1.f / (1.f + expf(-h3[co]));
}

// ---------------------------------------------------------------------------
// uaconv einsum + fused trailing 1x1 conv + lrelu.
// y[m,p] = sum_{n,k} x[n, p+off(k)] * spec[n,p] * spat[k,p] * Wk[m,n,k]
// fout[mo,p] = lrelu(sum_m cw[mo,m]*y[m,p] + cb[mo])
// Wk staged in LDS in two n-halves of 36 KB ([nl][k][m], m-contiguous).
__device__ __forceinline__ void ua_half(const float* __restrict__ xbase,
                                        const float* __restrict__ spec, int nbase,
                                        int p, int h, int x0,
                                        const float* sv, const float* wkt, float* acc) {
    for (int nl = 0; nl < 32; ++nl) {
        const float* xc = xbase + nl * P;
        float s = spec[(nbase + nl) * P + p];
        float q[9];
        #pragma unroll
        for (int kh = 0; kh < 3; ++kh) {
            int hh = h + kh - 1;
            bool hok = (unsigned)hh < 256u;
            #pragma unroll
            for (int kw = 0; kw < 3; ++kw) {
                int wx = x0 + kw - 1;
                float v = (hok && (unsigned)wx < 256u) ? xc[hh * WW + wx] : 0.f;
                q[kh * 3 + kw] = v * s * sv[kh * 3 + kw];
            }
        }
        const float* wb = wkt + nl * 288;
        #pragma unroll
        for (int k = 0; k < 9; ++k) {
            float qk = q[k];
            const float4* wp = (const float4*)(wb + k * 32);
            #pragma unroll
            for (int mq = 0; mq < 8; ++mq) {
                float4 wv = wp[mq];
                acc[mq * 4 + 0] = fmaf(qk, wv.x, acc[mq * 4 + 0]);
                acc[mq * 4 + 1] = fmaf(qk, wv.y, acc[mq * 4 + 1]);
                acc[mq * 4 + 2] = fmaf(qk, wv.z, acc[mq * 4 + 2]);
                acc[mq * 4 + 3] = fmaf(qk, wv.w, acc[mq * 4 + 3]);
            }
        }
    }
}

__global__ __launch_bounds__(256, 1) void uaconv2_k(
        const float* __restrict__ xa, const float* __restrict__ xb,
        const float* __restrict__ spec, const float* __restrict__ spat,
        const float* __restrict__ Wk,
        const float* __restrict__ cw, const float* __restrict__ cb,
        float* __restrict__ fout) {
    __shared__ float wkt[9216];   // [nl][k][m] for one 32-n half (36 KB)
    __shared__ float cwt[1024];   // [m][mo] transposed
    for (int i = threadIdx.x; i < 1024; i += 256) {
        int mo = i & 31, m = i >> 5;
        cwt[m * 32 + mo] = cw[mo * 32 + m];
    }
    for (int i = threadIdx.x; i < 9216; i += 256) {
        int m = i & 31;
        int rest = i >> 5;              // nl*9 + k
        wkt[i] = Wk[m * 576 + rest];    // nbase = 0
    }
    __syncthreads();

    int p = blockIdx.x * 256 + threadIdx.x;
    int h = p >> 8, x0 = p & 255;
    float sv[9];
    #pragma unroll
    for (int k = 0; k < 9; ++k) sv[k] = spat[k * P + p];
    float acc[32];
    #pragma unroll
    for (int m = 0; m < 32; ++m) acc[m] = 0.f;

    ua_half(xa, spec, 0, p, h, x0, sv, wkt, acc);

    __syncthreads();
    for (int i = threadIdx.x; i < 9216; i += 256) {
        int m = i & 31;
        int rest = i >> 5;
        wkt[i] = Wk[m * 576 + 288 + rest];   // nbase = 32
    }
    __syncthreads();

    ua_half(xb, spec, 32, p, h, x0, sv, wkt, acc);

    // fused 1x1 conv + lrelu
    float fo[32];
    #pragma unroll
    for (int mo = 0; mo < 32; ++mo) fo[mo] = cb[mo];
    #pragma unroll
    for (int m = 0; m < 32; ++m) {
        float av = acc[m];
        const float4* wp = (const float4*)&cwt[m * 32];
        #pragma unroll
        for (int mq = 0; mq < 8; ++mq) {
            float4 wv = wp[mq];
            fo[mq * 4 + 0] = fmaf(av, wv.x, fo[mq * 4 + 0]);
            fo[mq * 4 + 1] = fmaf(av, wv.y, fo[mq * 4 + 1]);
            fo[mq * 4 + 2] = fmaf(av, wv.z, fo[mq * 4 + 2]);
            fo[mq * 4 + 3] = fmaf(av, wv.w, fo[mq * 4 + 3]);
        }
    }
    #pragma unroll
    for (int mo = 0; mo < 32; ++mo) {
        float r = fo[mo];
        fout[mo * P + p] = r > 0.f ? r : 0.2f * r;
    }
}

// ---------------------------------------------------------------------------
extern "C" void kernel_launch(void* const* d_in, const int* in_sizes, int n_in,
                              void* d_out, int out_size, void* d_ws, size_t ws_size,
                              hipStream_t stream) {
    const float* F1        = (const float*)d_in[0];
    const float* ms        = (const float*)d_in[1];
    const float* pan       = (const float*)d_in[2];
    const float* masks_u   = (const float*)d_in[3];
    const float* ue_conv_w = (const float*)d_in[4];
    const float* ue_conv_b = (const float*)d_in[5];
    const float* ue_out_w  = (const float*)d_in[6];
    const float* ue_out_b  = (const float*)d_in[7];
    const float* ue_aue_w  = (const float*)d_in[8];
    const float* ue_aue_b  = (const float*)d_in[9];
    const float* conv1_w   = (const float*)d_in[10];
    const float* conv1_b   = (const float*)d_in[11];
    const float* conv2_w   = (const float*)d_in[12];
    const float* conv2_b   = (const float*)d_in[13];
    const float* spa1_w0 = (const float*)d_in[14];
    const float* spa1_b0 = (const float*)d_in[15];
    const float* spa1_w1 = (const float*)d_in[16];
    const float* spa1_b1 = (const float*)d_in[17];
    const float* spa1_w2 = (const float*)d_in[18];
    const float* spa1_b2 = (const float*)d_in[19];
    const float* spe1_w0 = (const float*)d_in[20];
    const float* spe1_b0 = (const float*)d_in[21];
    const float* spe1_w1 = (const float*)d_in[22];
    const float* spe1_b1 = (const float*)d_in[23];
    const float* spe1_w2 = (const float*)d_in[24];
    const float* spe1_b2 = (const float*)d_in[25];
    const float* ua1_w   = (const float*)d_in[26];
    const float* spa2_w0 = (const float*)d_in[27];
    const float* spa2_b0 = (const float*)d_in[28];
    const float* spa2_w1 = (const float*)d_in[29];
    const float* spa2_b1 = (const float*)d_in[30];
    const float* spa2_w2 = (const float*)d_in[31];
    const float* spa2_b2 = (const float*)d_in[32];
    const float* spe2_w0 = (const float*)d_in[33];
    const float* spe2_b0 = (const float*)d_in[34];
    const float* spe2_w1 = (const float*)d_in[35];
    const float* spe2_b1 = (const float*)d_in[36];
    const float* spe2_w2 = (const float*)d_in[37];
    const float* spe2_b2 = (const float*)d_in[38];
    const float* ua2_w   = (const float*)d_in[39];

    float* out  = (float*)d_out;
    float* AU   = out;             // 4*P
    float* EU   = out + 4 * P;     // 4*P
    float* MEAN = out + 8 * P;     // 4*P
    float* FOUT = out + 12 * P;    // 32*P

    float* ws   = (float*)d_ws;
    float* x    = ws;              // 64P
    float* spec = ws + 64 * P;     // 64P
    float* spat = ws + 128 * P;    // 9P
    float* f2   = ws + 137 * P;    // 32P

    dim3 blk(256);

    // x = conv3x3(F_1; 32->64), no act
    conv3x3_rb<32, 8, 4, 0><<<dim3(64, 8), blk, 0, stream>>>(F1, ue_conv_w, ue_conv_b, x);
    // EU / mean
    xsstats_k<<<dim3(256), blk, 0, stream>>>(x, masks_u, ue_out_w, ue_out_b, ms, EU, MEAN);
    // AU = sigmoid(conv3x3(x; 64->4))
    conv3x3_rb<64, 2, 2, 2><<<dim3(128, 2), blk, 0, stream>>>(x, ue_aue_w, ue_aue_b, AU);

    // ---- uaconv 1 (U = EU, inputs F1 || pan), fused conv1 -> f2 ----
    spa_fused_k<<<dim3(256), blk, 0, stream>>>(EU, spa1_w0, spa1_b0, spa1_w1, spa1_b1,
                                               spa1_w2, spa1_b2, spat, 0);
    spe_fused_k<<<dim3(256), blk, 0, stream>>>(EU, 0, spe1_w0, spe1_b0, spe1_w1, spe1_b1,
                                               spe1_w2, spe1_b2, spec);
    uaconv2_k<<<dim3(256), blk, 0, stream>>>(F1, pan, spec, spat, ua1_w, conv1_w, conv1_b, f2);

    // ---- uaconv 2 (U = 1-EU, inputs F1 || F_2), fused conv2 -> FOUT ----
    spa_fused_k<<<dim3(256), blk, 0, stream>>>(EU, spa2_w0, spa2_b0, spa2_w1, spa2_b1,
                                               spa2_w2, spa2_b2, spat, 1);
    spe_fused_k<<<dim3(256), blk, 0, stream>>>(EU, 1, spe2_w0, spe2_b0, spe2_w1, spe2_b1,
                                               spe2_w2, spe2_b2, spec);
    uaconv2_k<<<dim3(256), blk, 0, stream>>>(F1, f2, spec, spat, ua2_w, conv2_w, conv2_b, FOUT);
}